// Round 6
// baseline (222.674 us; speedup 1.0000x reference)
//
#include <hip/hip_runtime.h>

// B=4, C1=128, C2=64, H1=W1=128, H2=W2=256, G1=8, G2=16, BS1=8, BS2=16, nb=256.

// ---- workspace layout (float offsets) ----
#define GAP_OFF  0        // [768] atomic gap sums: [0,512)=x1 [b*128+c], [512,768)=x2 [b*64+c]
#define POS1_OFF 768      // [4*256*64]
#define POS2_OFF 66304    // [4*256*256]
// end 328448 floats = 1.25 MB

typedef __attribute__((ext_vector_type(8))) short short8;
typedef __attribute__((ext_vector_type(4))) float f32x4;
union U8 { short8 s; unsigned int u[4]; };

// ---------------- K1: single-pass gap+pos ----------------
// R6: gap reduction moved from LDS-transpose (33KB gbuf + barrier + half-idle reduce)
// to an in-register exchange-halving shuffle reduce: at step m lanes swap half their
// channel partials with lane^m and fold (32 shfl x1 / 17 shfl x2). Lane L ends owning
// the full 256-px sum of channel 4*bitrev(L)+wv -> one atomic. LDS 37.3->4KB, one
// barrier fewer, and launch_bounds(256,5) fits 5 blocks/CU -> 1280-block grid in ONE
// dispatch round. k_mrg is byte-identical to R5 (one variable per round).
__global__ __launch_bounds__(256, 5) void k_fuse(const float* __restrict__ x1,
                                                 const float* __restrict__ x2,
                                                 const float* __restrict__ w_p1,
                                                 const float* __restrict__ b_p1,
                                                 const float* __restrict__ w_p2,
                                                 const float* __restrict__ b_p2,
                                                 float* __restrict__ ws) {
  __shared__ float pbuf[1024];       // [wave][256 px] pos partials
  int blk = blockIdx.x, t = threadIdx.x;
  int wv = t >> 6, ln = t & 63;
  if (blk < 256) {
    int b = blk >> 6;
    int px0 = (blk & 63) << 8;
    const float* xb = x1 + ((size_t)b << 21) + px0 + (ln << 2);
    float4 pacc; pacc.x = pacc.y = pacc.z = pacc.w = 0.f;
    float gs[32];
#pragma unroll
    for (int i = 0; i < 32; ++i) {
      int c = (i << 2) + wv;
      float4 v = *(const float4*)(xb + ((size_t)c << 14));
      float wc = w_p1[c];
      pacc.x = fmaf(wc, v.x, pacc.x); pacc.y = fmaf(wc, v.y, pacc.y);
      pacc.z = fmaf(wc, v.z, pacc.z); pacc.w = fmaf(wc, v.w, pacc.w);
      gs[i] = (v.x + v.y) + (v.z + v.w);
    }
    *(float4*)&pbuf[(wv << 8) + (ln << 2)] = pacc;
    // exchange-halving reduce: 32 values x 64 lanes -> 1 value/lane (bits 0..4), then
    // fold lane^32. After step s, lanes with bit s set own the upper half of channels.
#pragma unroll
    for (int s = 0; s < 5; ++s) {
      int m = 1 << s;
      int half = 16 >> s;              // 16,8,4,2,1
      bool up = (ln & m) != 0;
#pragma unroll
      for (int i = 0; i < 16; ++i) {
        if (i < half) {
          float lo = gs[i], hi = gs[i + half];
          float send = up ? lo : hi;
          float recv = __shfl_xor(send, m, 64);
          gs[i] = (up ? hi : lo) + recv;
        }
      }
    }
    gs[0] += __shfl_xor(gs[0], 32, 64);
    // lane L owns channel slot bitrev5(L): 16*b0+8*b1+4*b2+2*b3+1*b4
    int cl = ((ln & 1) << 4) | ((ln & 2) << 2) | (ln & 4) | ((ln & 8) >> 2) | ((ln & 16) >> 4);
    if (ln < 32) atomicAdd(&ws[GAP_OFF + b * 128 + (cl << 2) + wv], gs[0]);
    __syncthreads();
    float s = (pbuf[t] + pbuf[256 + t]) + (pbuf[512 + t] + pbuf[768 + t]) + b_p1[0];
    int p = px0 + t, h = p >> 7, w0 = p & 127;
    int n = ((h >> 3) << 4) + (w0 >> 3);
    ws[POS1_OFF + ((b * 256 + n) << 6) + ((h & 7) << 3) + (w0 & 7)] = s;
  } else {
    int j = blk - 256;
    int b = j >> 8;
    int row = j & 255;
    const float* xb = x2 + ((size_t)b << 22) + (row << 8) + (ln << 2);
    float4 pacc; pacc.x = pacc.y = pacc.z = pacc.w = 0.f;
    float gs[16];
#pragma unroll
    for (int i = 0; i < 16; ++i) {
      int c = (i << 2) + wv;
      float4 v = *(const float4*)(xb + ((size_t)c << 16));
      float wc = w_p2[c];
      pacc.x = fmaf(wc, v.x, pacc.x); pacc.y = fmaf(wc, v.y, pacc.y);
      pacc.z = fmaf(wc, v.z, pacc.z); pacc.w = fmaf(wc, v.w, pacc.w);
      gs[i] = (v.x + v.y) + (v.z + v.w);
    }
    *(float4*)&pbuf[(wv << 8) + (ln << 2)] = pacc;
    // 16 values -> 1 (bits 0..3), then fold lane^16, lane^32
#pragma unroll
    for (int s = 0; s < 4; ++s) {
      int m = 1 << s;
      int half = 8 >> s;               // 8,4,2,1
      bool up = (ln & m) != 0;
#pragma unroll
      for (int i = 0; i < 8; ++i) {
        if (i < half) {
          float lo = gs[i], hi = gs[i + half];
          float send = up ? lo : hi;
          float recv = __shfl_xor(send, m, 64);
          gs[i] = (up ? hi : lo) + recv;
        }
      }
    }
    gs[0] += __shfl_xor(gs[0], 16, 64);
    gs[0] += __shfl_xor(gs[0], 32, 64);
    int cl = ((ln & 1) << 3) | ((ln & 2) << 1) | ((ln & 4) >> 1) | ((ln & 8) >> 3);
    if (ln < 16) atomicAdd(&ws[GAP_OFF + 512 + b * 64 + (cl << 2) + wv], gs[0]);
    __syncthreads();
    float s = (pbuf[t] + pbuf[256 + t]) + (pbuf[512 + t] + pbuf[768 + t]) + b_p2[0];
    int n = ((row >> 4) << 4) + (t >> 4);
    ws[POS2_OFF + ((b * 256 + n) << 8) + ((row & 15) << 4) + (t & 15)] = s;
  }
}

// ---------------- K2: merged attention + channel-attn weights + conv+BN+ReLU ----------------
// BYTE-IDENTICAL to R5 (41.5us-class structure, measured 40.3us, clean counters):
// grid 1024, 1 row/block, streaming S4 loads, no setprio, no max-shift, float4 w_lin.
__global__ __launch_bounds__(256, 4) void k_mrg(const float* __restrict__ x2,
                                                const float* __restrict__ w_lin,
                                                const float* __restrict__ b_lin,
                                                const float* __restrict__ w_c1,
                                                const float* __restrict__ b_c1,
                                                const float* __restrict__ w_c2,
                                                const float* __restrict__ b_c2,
                                                const float* __restrict__ w_f,
                                                const float* __restrict__ b_f,
                                                const float* __restrict__ gm,
                                                const float* __restrict__ bt,
                                                const float* __restrict__ ws,
                                                float* __restrict__ out) {
  __shared__ unsigned short aHi[4096];       // packed bf16 A-fragments [g=2i+ks][lane][8]
  __shared__ float P1[64], V[256], A2[256], T[256], spa_s[256];
  __shared__ float g1s[128], g2s[64], cw_l[64], p2s[64], p3s[64];
  const float L2E = 1.44269504088896f;
  const float kbn = 0.99999500003749969f;    // 1/sqrt(1+1e-5)
  int t = threadIdx.x;
  int blk = blockIdx.x;
  int b = blk >> 8, n = blk & 255;

  // S0: loads
  if (t < 128) g1s[t] = ws[GAP_OFF + b * 128 + t] * (1.f / 16384.f);
  if (t < 64)  g2s[t] = ws[GAP_OFF + 512 + b * 64 + t] * (1.f / 65536.f);
  if (t < 64)  P1[t] = ws[POS1_OFF + blk * 64 + t];
  float a = ws[POS2_OFF + blk * 256 + t];
  float a2 = a * L2E;
  A2[t] = a2;
  __syncthreads();

  // S1: x1t row (float4 w_lin); threads 0..7 also run the tiny channel-attn MLP
  float v = b_lin[t];
  const float4* wr4 = (const float4*)(w_lin + t * 64);
#pragma unroll
  for (int k = 0; k < 16; ++k) {
    float4 wv = wr4[k];
    float4 pv = *(float4*)&P1[k << 2];
    v = fmaf(wv.x, pv.x, v); v = fmaf(wv.y, pv.y, v);
    v = fmaf(wv.z, pv.z, v); v = fmaf(wv.w, pv.w, v);
  }
  V[t] = v;
  if (t < 8) {
    int g = t;
    const float* g1 = g1s + g * 16;
    const float* g2 = g2s + g * 8;
    float m1[8];
    for (int o = 0; o < 8; ++o) {
      float s = b_c1[o];
      for (int c = 0; c < 16; ++c) s = fmaf(w_c1[o * 16 + c], g1[c], s);
      m1[o] = fmaxf(s, 0.f);
    }
    float ss = 0.f;
    for (int p = 0; p < 8; ++p) {
      float s = b_c2[p];
      for (int c = 0; c < 8; ++c) s = fmaf(w_c2[p * 8 + c], g2[c], s);
      float r = fmaxf(s, 0.f);
      ss = fmaf(r, r, ss);
    }
    float lg[8], mx = -1e30f;
    for (int o = 0; o < 8; ++o) { lg[o] = m1[o] * ss; mx = fmaxf(mx, lg[o]); }
    float se = 0.f;
    for (int o = 0; o < 8; ++o) {
      lg[o] = __builtin_amdgcn_exp2f((lg[o] - mx) * L2E);
      se += lg[o];
    }
    float inv = 1.f / se;
    for (int o = 0; o < 8; ++o) cw_l[g * 8 + o] = lg[o] * inv;
  }
  __syncthreads();

  // S2: softmax denominator (no max-shift); threads 0..63 also fold P2/P3
  float d0 = 0.f, d1 = 0.f, d2 = 0.f, d3 = 0.f;
#pragma unroll 4
  for (int k = 0; k < 256; k += 4) {
    float4 vv = *(float4*)&V[k];
    d0 += __builtin_amdgcn_exp2f(a2 * vv.x);
    d1 += __builtin_amdgcn_exp2f(a2 * vv.y);
    d2 += __builtin_amdgcn_exp2f(a2 * vv.z);
    d3 += __builtin_amdgcn_exp2f(a2 * vv.w);
  }
  float den = (d0 + d1) + (d2 + d3);
  T[t] = a / den;
  if (t < 64) {
    const float4* wrow = (const float4*)(w_f + t * 64);
    float s0 = 0.f, s1 = 0.f, s2 = 0.f, s3 = 0.f;
#pragma unroll
    for (int k = 0; k < 16; ++k) {
      float4 wv = wrow[k];
      s0 += wv.x; s1 += wv.y; s2 += wv.z; s3 += wv.w;
    }
    float A = kbn * gm[t];
    p2s[t] = ((s0 + s1) + (s2 + s3)) * A;
    p3s[t] = fmaf(b_f[t], A, bt[t]);
  }
  __syncthreads();

  // S3: attention pass 2 (spa row) + bf16 A-fragment build
  float c0 = 0.f, c1 = 0.f, c2 = 0.f, c3 = 0.f;
#pragma unroll 4
  for (int q = 0; q < 256; q += 4) {
    float4 aq = *(float4*)&A2[q];
    float4 tq = *(float4*)&T[q];
    c0 = fmaf(tq.x, __builtin_amdgcn_exp2f(aq.x * v), c0);
    c1 = fmaf(tq.y, __builtin_amdgcn_exp2f(aq.y * v), c1);
    c2 = fmaf(tq.z, __builtin_amdgcn_exp2f(aq.z * v), c2);
    c3 = fmaf(tq.w, __builtin_amdgcn_exp2f(aq.w * v), c3);
  }
  spa_s[t] = (c0 + c1) + (c2 + c3);
  // A-pack: pair E = g*256 + laneE*4 + jp  ==  (g<<8) + t  (laneE = t>>2, jp = t&3).
  // Element (g, laneE, slot): o = 16*(g>>1) + (laneE&15), c = 32*(g&1) + 8*(laneE>>4) + slot.
  {
    unsigned int* aU = (unsigned int*)aHi;
#pragma unroll
    for (int gi = 0; gi < 4; ++gi) {
      int o = (gi << 4) + ((t >> 2) & 15);
      float ga = kbn * gm[o];
#pragma unroll
      for (int gk = 0; gk < 2; ++gk) {
        int c = (gk << 5) + ((t >> 6) << 3) + ((t & 3) << 1);
        float2 wf2 = *(const float2*)(w_f + (o << 6) + c);
        float v0 = wf2.x * cw_l[c] * ga;
        float v1 = wf2.y * cw_l[c + 1] * ga;
        unsigned int u0 = __float_as_uint(v0), u1 = __float_as_uint(v1);
        unsigned int r0 = (u0 + 0x7FFFu + ((u0 >> 16) & 1u)) >> 16;          // bf16 RNE lo-slot
        unsigned int r1 = (u1 + 0x7FFFu + ((u1 >> 16) & 1u)) & 0xFFFF0000u;  // bf16 RNE hi-slot
        aU[(((gi << 1) + gk) << 8) + t] = r0 | r1;
      }
    }
  }
  __syncthreads();

  // S4: conv for row n via MFMA. Wave w owns px [64w,64w+64); frag (i,jt):
  // rows o=16i+4*krow+r, cols p=64w+16jt+pcol. K=64 consumed per jt -> only 4 live accs.
  {
    int l = t & 63;
    int w = t >> 6;
    int pcol = l & 15;
    int krow = l >> 4;
    short8 afr[4][2];
#pragma unroll
    for (int i = 0; i < 4; ++i)
#pragma unroll
      for (int ks = 0; ks < 2; ++ks)
        afr[i][ks] = *(const short8*)&aHi[(((i << 1) + ks) << 9) + (l << 3)];
    float p2v[16], p3v[16];
#pragma unroll
    for (int i = 0; i < 4; ++i)
#pragma unroll
      for (int r = 0; r < 4; ++r) {
        int o = (i << 4) + (krow << 2) + r;
        p2v[(i << 2) + r] = p2s[o];
        p3v[(i << 2) + r] = p3s[o];
      }
    const float* xbase = x2 + ((size_t)b << 22) + (n << 8) + (w << 6) + pcol
                         + ((size_t)(krow << 3) << 16);
    float* obase = out + ((size_t)b << 22) + (n << 8) + (w << 6) + pcol;
    for (int jt = 0; jt < 4; ++jt) {
      const float* xp = xbase + (jt << 4);
      float xv[2][8];
#pragma unroll
      for (int ks = 0; ks < 2; ++ks)
#pragma unroll
        for (int j = 0; j < 8; ++j)
          xv[ks][j] = xp[(size_t)((ks << 5) + j) << 16];
      U8 bh[2], bl[2];
#pragma unroll
      for (int ks = 0; ks < 2; ++ks)
#pragma unroll
        for (int q = 0; q < 4; ++q) {
          float f0 = xv[ks][2 * q], f1 = xv[ks][2 * q + 1];
          unsigned int u0 = __float_as_uint(f0), u1 = __float_as_uint(f1);
          unsigned int h0 = u0 & 0xFFFF0000u, h1 = u1 & 0xFFFF0000u;
          bh[ks].u[q] = (u0 >> 16) | h1;                       // truncated hi bf16 pair
          float e0 = f0 - __uint_as_float(h0);
          float e1 = f1 - __uint_as_float(h1);
          bl[ks].u[q] = (__float_as_uint(e0) >> 16) | (__float_as_uint(e1) & 0xFFFF0000u);
        }
      f32x4 acc[4] = {};
#pragma unroll
      for (int i = 0; i < 4; ++i) {
#pragma unroll
        for (int ks = 0; ks < 2; ++ks) {
          acc[i] = __builtin_amdgcn_mfma_f32_16x16x32_bf16(afr[i][ks], bh[ks].s, acc[i], 0, 0, 0);
          acc[i] = __builtin_amdgcn_mfma_f32_16x16x32_bf16(afr[i][ks], bl[ks].s, acc[i], 0, 0, 0);
        }
      }
      float spa_p = spa_s[(w << 6) + (jt << 4) + pcol];
#pragma unroll
      for (int i = 0; i < 4; ++i) {
#pragma unroll
        for (int r = 0; r < 4; ++r) {
          int o = (i << 4) + (krow << 2) + r;
          float val = fmaf(spa_p, p2v[(i << 2) + r], acc[i][r] + p3v[(i << 2) + r]);
          obase[(jt << 4) + ((size_t)o << 16)] = fmaxf(val, 0.f);
        }
      }
    }
  }
}

extern "C" void kernel_launch(void* const* d_in, const int* in_sizes, int n_in,
                              void* d_out, int out_size, void* d_ws, size_t ws_size,
                              hipStream_t stream) {
  const float* x1   = (const float*)d_in[0];
  const float* x2   = (const float*)d_in[1];
  const float* w_c1 = (const float*)d_in[2];
  const float* b_c1 = (const float*)d_in[3];
  const float* w_c2 = (const float*)d_in[4];
  const float* b_c2 = (const float*)d_in[5];
  const float* w_p1 = (const float*)d_in[6];
  const float* b_p1 = (const float*)d_in[7];
  const float* w_p2 = (const float*)d_in[8];
  const float* b_p2 = (const float*)d_in[9];
  const float* w_lin= (const float*)d_in[10];
  const float* b_lin= (const float*)d_in[11];
  const float* w_f  = (const float*)d_in[12];
  const float* b_f  = (const float*)d_in[13];
  const float* gmm  = (const float*)d_in[14];
  const float* btt  = (const float*)d_in[15];
  float* ws  = (float*)d_ws;
  float* out = (float*)d_out;

  // zero the atomic gap-sum region (ws is re-poisoned 0xAA before every launch)
  hipMemsetAsync(ws, 0, 768 * sizeof(float), stream);
  hipLaunchKernelGGL(k_fuse, dim3(1280), dim3(256), 0, stream, x1, x2, w_p1, b_p1, w_p2, b_p2, ws);
  hipLaunchKernelGGL(k_mrg,  dim3(1024), dim3(256), 0, stream, x2, w_lin, b_lin,
                     w_c1, b_c1, w_c2, b_c2, w_f, b_f, gmm, btt, ws, out);
}

// Round 7
// 194.425 us; speedup vs baseline: 1.1453x; 1.1453x over previous
//
#include <hip/hip_runtime.h>

// B=4, C1=128, C2=64, H1=W1=128, H2=W2=256, G1=8, G2=16, BS1=8, BS2=16, nb=256.

// ---- workspace layout (float offsets) ----
#define GAP_OFF  0        // [768] atomic gap sums: [0,512)=x1 [b*128+c], [512,768)=x2 [b*64+c]
#define POS1_OFF 768      // [4*256*64]
#define POS2_OFF 66304    // [4*256*256]
// end 328448 floats = 1.25 MB

typedef __attribute__((ext_vector_type(8))) short short8;
typedef __attribute__((ext_vector_type(4))) float f32x4;
union U8 { short8 s; unsigned int u[4]; };

// ---------------- K1: single-pass gap+pos (R0/R5 monolithic form — best measured) ----------------
// R6's in-register shuffle reduce regressed hard (60us, VALUBusy 3.3% -> pure latency
// stall; the gbuf stores in this form keep the load stream pipelined). REVERTED exactly.
__global__ __launch_bounds__(256) void k_fuse(const float* __restrict__ x1,
                                              const float* __restrict__ x2,
                                              const float* __restrict__ w_p1,
                                              const float* __restrict__ b_p1,
                                              const float* __restrict__ w_p2,
                                              const float* __restrict__ b_p2,
                                              float* __restrict__ ws) {
  __shared__ float gbuf[128 * 65];   // [row][lane], stride 65 kills bank conflicts
  __shared__ float pbuf[1024];       // [wave][256 px] pos partials
  int blk = blockIdx.x, t = threadIdx.x;
  int wv = t >> 6, ln = t & 63;
  if (blk < 256) {
    int b = blk >> 6;
    int px0 = (blk & 63) << 8;
    const float* xb = x1 + ((size_t)b << 21) + px0 + (ln << 2);
    float4 pacc; pacc.x = pacc.y = pacc.z = pacc.w = 0.f;
    float gs[32];
#pragma unroll
    for (int i = 0; i < 32; ++i) {
      int c = (i << 2) + wv;
      float4 v = *(const float4*)(xb + ((size_t)c << 14));
      float wc = w_p1[c];
      pacc.x = fmaf(wc, v.x, pacc.x); pacc.y = fmaf(wc, v.y, pacc.y);
      pacc.z = fmaf(wc, v.z, pacc.z); pacc.w = fmaf(wc, v.w, pacc.w);
      gs[i] = (v.x + v.y) + (v.z + v.w);
    }
#pragma unroll
    for (int i = 0; i < 32; ++i) gbuf[((wv << 5) + i) * 65 + ln] = gs[i];
    *(float4*)&pbuf[(wv << 8) + (ln << 2)] = pacc;
    __syncthreads();
    if (t < 128) {
      int w2 = t >> 5, i2 = t & 31;
      int c = (i2 << 2) + w2;
      const float* gp = &gbuf[t * 65];
      float s0 = 0.f, s1 = 0.f, s2 = 0.f, s3 = 0.f;
#pragma unroll
      for (int k = 0; k < 64; k += 4) { s0 += gp[k]; s1 += gp[k+1]; s2 += gp[k+2]; s3 += gp[k+3]; }
      atomicAdd(&ws[GAP_OFF + b * 128 + c], (s0 + s1) + (s2 + s3));
    }
    float s = (pbuf[t] + pbuf[256 + t]) + (pbuf[512 + t] + pbuf[768 + t]) + b_p1[0];
    int p = px0 + t, h = p >> 7, w0 = p & 127;
    int n = ((h >> 3) << 4) + (w0 >> 3);
    ws[POS1_OFF + ((b * 256 + n) << 6) + ((h & 7) << 3) + (w0 & 7)] = s;
  } else {
    int j = blk - 256;
    int b = j >> 8;
    int row = j & 255;
    const float* xb = x2 + ((size_t)b << 22) + (row << 8) + (ln << 2);
    float4 pacc; pacc.x = pacc.y = pacc.z = pacc.w = 0.f;
    float gs[16];
#pragma unroll
    for (int i = 0; i < 16; ++i) {
      int c = (i << 2) + wv;
      float4 v = *(const float4*)(xb + ((size_t)c << 16));
      float wc = w_p2[c];
      pacc.x = fmaf(wc, v.x, pacc.x); pacc.y = fmaf(wc, v.y, pacc.y);
      pacc.z = fmaf(wc, v.z, pacc.z); pacc.w = fmaf(wc, v.w, pacc.w);
      gs[i] = (v.x + v.y) + (v.z + v.w);
    }
#pragma unroll
    for (int i = 0; i < 16; ++i) gbuf[((wv << 4) + i) * 65 + ln] = gs[i];
    *(float4*)&pbuf[(wv << 8) + (ln << 2)] = pacc;
    __syncthreads();
    if (t < 64) {
      int w2 = t >> 4, i2 = t & 15;
      int c = (i2 << 2) + w2;
      const float* gp = &gbuf[t * 65];
      float s0 = 0.f, s1 = 0.f, s2 = 0.f, s3 = 0.f;
#pragma unroll
      for (int k = 0; k < 64; k += 4) { s0 += gp[k]; s1 += gp[k+1]; s2 += gp[k+2]; s3 += gp[k+3]; }
      atomicAdd(&ws[GAP_OFF + 512 + b * 64 + c], (s0 + s1) + (s2 + s3));
    }
    float s = (pbuf[t] + pbuf[256 + t]) + (pbuf[512 + t] + pbuf[768 + t]) + b_p2[0];
    int n = ((row >> 4) << 4) + (t >> 4);
    ws[POS2_OFF + ((b * 256 + n) << 8) + ((row & 15) << 4) + (t & 15)] = s;
  }
}

// ---------------- K2: merged attention + channel-attn weights + conv+BN+ReLU ----------------
// R7 = R5's proven k_mrg (40.3us, clean counters) with one semantics-free micro-delta:
// S0 loads spread across thread groups (t<128: g1s, 128..191: g2s, 192..255: P1)
// instead of stacking three conditional loads on the low threads.
__global__ __launch_bounds__(256, 4) void k_mrg(const float* __restrict__ x2,
                                                const float* __restrict__ w_lin,
                                                const float* __restrict__ b_lin,
                                                const float* __restrict__ w_c1,
                                                const float* __restrict__ b_c1,
                                                const float* __restrict__ w_c2,
                                                const float* __restrict__ b_c2,
                                                const float* __restrict__ w_f,
                                                const float* __restrict__ b_f,
                                                const float* __restrict__ gm,
                                                const float* __restrict__ bt,
                                                const float* __restrict__ ws,
                                                float* __restrict__ out) {
  __shared__ unsigned short aHi[4096];       // packed bf16 A-fragments [g=2i+ks][lane][8]
  __shared__ float P1[64], V[256], A2[256], T[256], spa_s[256];
  __shared__ float g1s[128], g2s[64], cw_l[64], p2s[64], p3s[64];
  const float L2E = 1.44269504088896f;
  const float kbn = 0.99999500003749969f;    // 1/sqrt(1+1e-5)
  int t = threadIdx.x;
  int blk = blockIdx.x;
  int b = blk >> 8, n = blk & 255;

  // S0: loads (spread across thread groups; all consumed after the barrier)
  if (t < 128)      g1s[t]       = ws[GAP_OFF + b * 128 + t] * (1.f / 16384.f);
  else if (t < 192) g2s[t - 128] = ws[GAP_OFF + 512 + b * 64 + (t - 128)] * (1.f / 65536.f);
  else              P1[t - 192]  = ws[POS1_OFF + blk * 64 + (t - 192)];
  float a = ws[POS2_OFF + blk * 256 + t];
  float a2 = a * L2E;
  A2[t] = a2;
  __syncthreads();

  // S1: x1t row (float4 w_lin); threads 0..7 also run the tiny channel-attn MLP
  float v = b_lin[t];
  const float4* wr4 = (const float4*)(w_lin + t * 64);
#pragma unroll
  for (int k = 0; k < 16; ++k) {
    float4 wv = wr4[k];
    float4 pv = *(float4*)&P1[k << 2];
    v = fmaf(wv.x, pv.x, v); v = fmaf(wv.y, pv.y, v);
    v = fmaf(wv.z, pv.z, v); v = fmaf(wv.w, pv.w, v);
  }
  V[t] = v;
  if (t < 8) {
    int g = t;
    const float* g1 = g1s + g * 16;
    const float* g2 = g2s + g * 8;
    float m1[8];
    for (int o = 0; o < 8; ++o) {
      float s = b_c1[o];
      for (int c = 0; c < 16; ++c) s = fmaf(w_c1[o * 16 + c], g1[c], s);
      m1[o] = fmaxf(s, 0.f);
    }
    float ss = 0.f;
    for (int p = 0; p < 8; ++p) {
      float s = b_c2[p];
      for (int c = 0; c < 8; ++c) s = fmaf(w_c2[p * 8 + c], g2[c], s);
      float r = fmaxf(s, 0.f);
      ss = fmaf(r, r, ss);
    }
    float lg[8], mx = -1e30f;
    for (int o = 0; o < 8; ++o) { lg[o] = m1[o] * ss; mx = fmaxf(mx, lg[o]); }
    float se = 0.f;
    for (int o = 0; o < 8; ++o) {
      lg[o] = __builtin_amdgcn_exp2f((lg[o] - mx) * L2E);
      se += lg[o];
    }
    float inv = 1.f / se;
    for (int o = 0; o < 8; ++o) cw_l[g * 8 + o] = lg[o] * inv;
  }
  __syncthreads();

  // S2: softmax denominator (no max-shift); threads 0..63 also fold P2/P3
  float d0 = 0.f, d1 = 0.f, d2 = 0.f, d3 = 0.f;
#pragma unroll 4
  for (int k = 0; k < 256; k += 4) {
    float4 vv = *(float4*)&V[k];
    d0 += __builtin_amdgcn_exp2f(a2 * vv.x);
    d1 += __builtin_amdgcn_exp2f(a2 * vv.y);
    d2 += __builtin_amdgcn_exp2f(a2 * vv.z);
    d3 += __builtin_amdgcn_exp2f(a2 * vv.w);
  }
  float den = (d0 + d1) + (d2 + d3);
  T[t] = a / den;
  if (t < 64) {
    const float4* wrow = (const float4*)(w_f + t * 64);
    float s0 = 0.f, s1 = 0.f, s2 = 0.f, s3 = 0.f;
#pragma unroll
    for (int k = 0; k < 16; ++k) {
      float4 wv = wrow[k];
      s0 += wv.x; s1 += wv.y; s2 += wv.z; s3 += wv.w;
    }
    float A = kbn * gm[t];
    p2s[t] = ((s0 + s1) + (s2 + s3)) * A;
    p3s[t] = fmaf(b_f[t], A, bt[t]);
  }
  __syncthreads();

  // S3: attention pass 2 (spa row) + bf16 A-fragment build
  float c0 = 0.f, c1 = 0.f, c2 = 0.f, c3 = 0.f;
#pragma unroll 4
  for (int q = 0; q < 256; q += 4) {
    float4 aq = *(float4*)&A2[q];
    float4 tq = *(float4*)&T[q];
    c0 = fmaf(tq.x, __builtin_amdgcn_exp2f(aq.x * v), c0);
    c1 = fmaf(tq.y, __builtin_amdgcn_exp2f(aq.y * v), c1);
    c2 = fmaf(tq.z, __builtin_amdgcn_exp2f(aq.z * v), c2);
    c3 = fmaf(tq.w, __builtin_amdgcn_exp2f(aq.w * v), c3);
  }
  spa_s[t] = (c0 + c1) + (c2 + c3);
  // A-pack: pair E = g*256 + laneE*4 + jp  ==  (g<<8) + t  (laneE = t>>2, jp = t&3).
  // Element (g, laneE, slot): o = 16*(g>>1) + (laneE&15), c = 32*(g&1) + 8*(laneE>>4) + slot.
  {
    unsigned int* aU = (unsigned int*)aHi;
#pragma unroll
    for (int gi = 0; gi < 4; ++gi) {
      int o = (gi << 4) + ((t >> 2) & 15);
      float ga = kbn * gm[o];
#pragma unroll
      for (int gk = 0; gk < 2; ++gk) {
        int c = (gk << 5) + ((t >> 6) << 3) + ((t & 3) << 1);
        float2 wf2 = *(const float2*)(w_f + (o << 6) + c);
        float v0 = wf2.x * cw_l[c] * ga;
        float v1 = wf2.y * cw_l[c + 1] * ga;
        unsigned int u0 = __float_as_uint(v0), u1 = __float_as_uint(v1);
        unsigned int r0 = (u0 + 0x7FFFu + ((u0 >> 16) & 1u)) >> 16;          // bf16 RNE lo-slot
        unsigned int r1 = (u1 + 0x7FFFu + ((u1 >> 16) & 1u)) & 0xFFFF0000u;  // bf16 RNE hi-slot
        aU[(((gi << 1) + gk) << 8) + t] = r0 | r1;
      }
    }
  }
  __syncthreads();

  // S4: conv for row n via MFMA. Wave w owns px [64w,64w+64); frag (i,jt):
  // rows o=16i+4*krow+r, cols p=64w+16jt+pcol. K=64 consumed per jt -> only 4 live accs.
  {
    int l = t & 63;
    int w = t >> 6;
    int pcol = l & 15;
    int krow = l >> 4;
    short8 afr[4][2];
#pragma unroll
    for (int i = 0; i < 4; ++i)
#pragma unroll
      for (int ks = 0; ks < 2; ++ks)
        afr[i][ks] = *(const short8*)&aHi[(((i << 1) + ks) << 9) + (l << 3)];
    float p2v[16], p3v[16];
#pragma unroll
    for (int i = 0; i < 4; ++i)
#pragma unroll
      for (int r = 0; r < 4; ++r) {
        int o = (i << 4) + (krow << 2) + r;
        p2v[(i << 2) + r] = p2s[o];
        p3v[(i << 2) + r] = p3s[o];
      }
    const float* xbase = x2 + ((size_t)b << 22) + (n << 8) + (w << 6) + pcol
                         + ((size_t)(krow << 3) << 16);
    float* obase = out + ((size_t)b << 22) + (n << 8) + (w << 6) + pcol;
    for (int jt = 0; jt < 4; ++jt) {
      const float* xp = xbase + (jt << 4);
      float xv[2][8];
#pragma unroll
      for (int ks = 0; ks < 2; ++ks)
#pragma unroll
        for (int j = 0; j < 8; ++j)
          xv[ks][j] = xp[(size_t)((ks << 5) + j) << 16];
      U8 bh[2], bl[2];
#pragma unroll
      for (int ks = 0; ks < 2; ++ks)
#pragma unroll
        for (int q = 0; q < 4; ++q) {
          float f0 = xv[ks][2 * q], f1 = xv[ks][2 * q + 1];
          unsigned int u0 = __float_as_uint(f0), u1 = __float_as_uint(f1);
          unsigned int h0 = u0 & 0xFFFF0000u, h1 = u1 & 0xFFFF0000u;
          bh[ks].u[q] = (u0 >> 16) | h1;                       // truncated hi bf16 pair
          float e0 = f0 - __uint_as_float(h0);
          float e1 = f1 - __uint_as_float(h1);
          bl[ks].u[q] = (__float_as_uint(e0) >> 16) | (__float_as_uint(e1) & 0xFFFF0000u);
        }
      f32x4 acc[4] = {};
#pragma unroll
      for (int i = 0; i < 4; ++i) {
#pragma unroll
        for (int ks = 0; ks < 2; ++ks) {
          acc[i] = __builtin_amdgcn_mfma_f32_16x16x32_bf16(afr[i][ks], bh[ks].s, acc[i], 0, 0, 0);
          acc[i] = __builtin_amdgcn_mfma_f32_16x16x32_bf16(afr[i][ks], bl[ks].s, acc[i], 0, 0, 0);
        }
      }
      float spa_p = spa_s[(w << 6) + (jt << 4) + pcol];
#pragma unroll
      for (int i = 0; i < 4; ++i) {
#pragma unroll
        for (int r = 0; r < 4; ++r) {
          int o = (i << 4) + (krow << 2) + r;
          float val = fmaf(spa_p, p2v[(i << 2) + r], acc[i][r] + p3v[(i << 2) + r]);
          obase[(jt << 4) + ((size_t)o << 16)] = fmaxf(val, 0.f);
        }
      }
    }
  }
}

extern "C" void kernel_launch(void* const* d_in, const int* in_sizes, int n_in,
                              void* d_out, int out_size, void* d_ws, size_t ws_size,
                              hipStream_t stream) {
  const float* x1   = (const float*)d_in[0];
  const float* x2   = (const float*)d_in[1];
  const float* w_c1 = (const float*)d_in[2];
  const float* b_c1 = (const float*)d_in[3];
  const float* w_c2 = (const float*)d_in[4];
  const float* b_c2 = (const float*)d_in[5];
  const float* w_p1 = (const float*)d_in[6];
  const float* b_p1 = (const float*)d_in[7];
  const float* w_p2 = (const float*)d_in[8];
  const float* b_p2 = (const float*)d_in[9];
  const float* w_lin= (const float*)d_in[10];
  const float* b_lin= (const float*)d_in[11];
  const float* w_f  = (const float*)d_in[12];
  const float* b_f  = (const float*)d_in[13];
  const float* gmm  = (const float*)d_in[14];
  const float* btt  = (const float*)d_in[15];
  float* ws  = (float*)d_ws;
  float* out = (float*)d_out;

  // zero the atomic gap-sum region (ws is re-poisoned 0xAA before every launch)
  hipMemsetAsync(ws, 0, 768 * sizeof(float), stream);
  hipLaunchKernelGGL(k_fuse, dim3(1280), dim3(256), 0, stream, x1, x2, w_p1, b_p1, w_p2, b_p2, ws);
  hipLaunchKernelGGL(k_mrg,  dim3(1024), dim3(256), 0, stream, x2, w_lin, b_lin,
                     w_c1, b_c1, w_c2, b_c2, w_f, b_f, gmm, btt, ws, out);
}